// Round 14
// baseline (143.208 us; speedup 1.0000x reference)
//
#include <hip/hip_runtime.h>
#include <math.h>

// FM model: out[s] = sigmoid(0.5*sum_e((sum_f v)^2 - sum_f v^2) + sum_f linear)
// user[16384,20,33], ctx[16384,10,33], doc[16384,30,33]
//
// R9 post-mortem: VGPR=24 proves the compiler serialized the 8-load unroll
// (accumulate-as-arrive, ~2-3 loads in flight -> ~1KB/CU outstanding ->
// Little's law caps at the observed ~3 TB/s effective). Same root cause as
// R6: compiler register-pressure heuristic defeats source-level MLP.
// R13: volatile inline-asm global_load_dwordx4 x8 into named registers —
// unreorderable, unserializable -> 128 B/lane in flight (8 KB/wave).
// Then s_waitcnt vmcnt(0) + sched_barrier(0) (rule-18 fence), then math.
// Round 7 tail: lanes rg>=4 load a duplicate row and mask by 0.

#define NS 16384

typedef float v4f __attribute__((ext_vector_type(4)));

__global__ __launch_bounds__(256) void fm_kernel(
    const float* __restrict__ user,
    const float* __restrict__ ctx,
    const float* __restrict__ doc,
    float* __restrict__ out) {
  const int tid = threadIdx.x;
  const int w   = tid >> 6;          // wave in block
  const int l   = tid & 63;          // lane
  const int s   = blockIdx.x * 4 + w;

  const int k  = l & 7;              // element group: e in [4k, 4k+4)
  const int rg = l >> 3;             // row group (0..7)

  const float* __restrict__ ub = user + (size_t)s * 660;
  const float* __restrict__ cb = ctx  + (size_t)s * 330;
  const float* __restrict__ db = doc  + (size_t)s * 990;

  // row r (0..59) -> row start (33-float stride within each array)
  auto rowptr = [&](int r) -> const float* {
    return r < 20 ? ub + r * 33
         : (r < 30 ? cb + (r - 20) * 33
                   : db + (r - 30) * 33);
  };

  // linear terms (compiler-scheduled; in flight alongside the asm loads)
  float lin = 0.f;
  if (l < 60) lin = rowptr(l)[32];

  // 8 round addresses; round 7 lanes rg>=4 duplicate a valid row (masked 0)
  const float* a0 = rowptr(     rg) + 4 * k;
  const float* a1 = rowptr( 8 + rg) + 4 * k;
  const float* a2 = rowptr(16 + rg) + 4 * k;
  const float* a3 = rowptr(24 + rg) + 4 * k;
  const float* a4 = rowptr(32 + rg) + 4 * k;
  const float* a5 = rowptr(40 + rg) + 4 * k;
  const float* a6 = rowptr(48 + rg) + 4 * k;
  const float* a7 = rowptr(56 + (rg & 3)) + 4 * k;

  // 8 loads issued back-to-back, all co-live (unsinkable, unserializable)
  v4f x0, x1, x2, x3, x4, x5, x6, x7;
  asm volatile("global_load_dwordx4 %0, %1, off" : "=v"(x0) : "v"(a0));
  asm volatile("global_load_dwordx4 %0, %1, off" : "=v"(x1) : "v"(a1));
  asm volatile("global_load_dwordx4 %0, %1, off" : "=v"(x2) : "v"(a2));
  asm volatile("global_load_dwordx4 %0, %1, off" : "=v"(x3) : "v"(a3));
  asm volatile("global_load_dwordx4 %0, %1, off" : "=v"(x4) : "v"(a4));
  asm volatile("global_load_dwordx4 %0, %1, off" : "=v"(x5) : "v"(a5));
  asm volatile("global_load_dwordx4 %0, %1, off" : "=v"(x6) : "v"(a6));
  asm volatile("global_load_dwordx4 %0, %1, off" : "=v"(x7) : "v"(a7));
  asm volatile("s_waitcnt vmcnt(0)" ::: "memory");
  __builtin_amdgcn_sched_barrier(0);   // rule 18: no VALU hoists above the wait

  float s0 = 0.f, s1 = 0.f, s2 = 0.f, s3 = 0.f, q = 0.f;

#define ACC(x) do {                                   \
    s0 += (x)[0]; s1 += (x)[1];                       \
    s2 += (x)[2]; s3 += (x)[3];                       \
    q = fmaf((x)[0], (x)[0], fmaf((x)[1], (x)[1],     \
        fmaf((x)[2], (x)[2], fmaf((x)[3], (x)[3], q))));} while (0)
  ACC(x0); ACC(x1); ACC(x2); ACC(x3); ACC(x4); ACC(x5); ACC(x6);
#undef ACC

  // round 7: masked (rows 56..59 only exist for rg<4)
  const float m7 = (rg < 4) ? 1.f : 0.f;
  s0 = fmaf(m7, x7[0], s0);
  s1 = fmaf(m7, x7[1], s1);
  s2 = fmaf(m7, x7[2], s2);
  s3 = fmaf(m7, x7[3], s3);
  float dot7 = x7[0] * x7[0] + x7[1] * x7[1] + x7[2] * x7[2] + x7[3] * x7[3];
  q = fmaf(m7, dot7, q);

  // phase 1: reduce over the 8 row-groups (masks 8,16,32)
#pragma unroll
  for (int m = 8; m <= 32; m <<= 1) {
    s0  += __shfl_xor(s0,  m, 64);
    s1  += __shfl_xor(s1,  m, 64);
    s2  += __shfl_xor(s2,  m, 64);
    s3  += __shfl_xor(s3,  m, 64);
    q   += __shfl_xor(q,   m, 64);
    lin += __shfl_xor(lin, m, 64);
  }

  // per-k-class cross term: sum_{e in class} S_e^2 - Q_e
  float pp = s0 * s0 + s1 * s1 + s2 * s2 + s3 * s3 - q;

  // phase 2: sum the 8 k-classes (masks 1,2,4)
#pragma unroll
  for (int m = 1; m <= 4; m <<= 1) {
    pp  += __shfl_xor(pp,  m, 64);
    lin += __shfl_xor(lin, m, 64);
  }

  if (l == 0) {
    float logit = fmaf(0.5f, pp, lin);
    out[s] = 1.f / (1.f + expf(-logit));
  }
}

extern "C" void kernel_launch(void* const* d_in, const int* in_sizes, int n_in,
                              void* d_out, int out_size, void* d_ws, size_t ws_size,
                              hipStream_t stream) {
  const float* user = (const float*)d_in[0];
  const float* ctx  = (const float*)d_in[1];
  const float* doc  = (const float*)d_in[2];
  float* out = (float*)d_out;

  // wave-per-sample: 256 threads = 4 samples/block, 4096 blocks
  dim3 block(256);
  dim3 grid(NS / 4);
  fm_kernel<<<grid, block, 0, stream>>>(user, ctx, doc, out);
}